// Round 10
// baseline (568.756 us; speedup 1.0000x reference)
//
#include <hip/hip_runtime.h>
#include <math.h>

#define NROWS 16384
#define GATES 5
#define HDIM 512
#define KPAD 416   // stage-1 K: 400 real cols padded to 13*32

using bf16x8 = __attribute__((ext_vector_type(8))) short;
using f32x4  = __attribute__((ext_vector_type(4))) float;

__device__ inline float b2f(unsigned short s) {
  unsigned int u = ((unsigned int)s) << 16;
  return __builtin_bit_cast(float, u);
}
__device__ inline unsigned short f2b(float f) {
  unsigned int u = __builtin_bit_cast(unsigned int, f);
  u += 0x7fffu + ((u >> 16) & 1u);   // RNE
  return (unsigned short)(u >> 16);
}

__device__ inline float fast_sigmoid(float x) {
  float t = __builtin_amdgcn_exp2f(-1.4426950408889634f * x);
  return __builtin_amdgcn_rcpf(1.0f + t);
}
__device__ inline float fast_tanh(float x) {
  float t = __builtin_amdgcn_exp2f(2.8853900817779268f * x);
  return 1.0f - 2.0f * __builtin_amdgcn_rcpf(1.0f + t);
}

__device__ inline void gload_lds16(const unsigned short* g, unsigned short* l) {
  __builtin_amdgcn_global_load_lds(
      (const __attribute__((address_space(1))) unsigned int*)(g),
      (__attribute__((address_space(3))) unsigned int*)(l), 16, 0, 0);
}

// ---------------- packing / conversion kernels (f32 -> bf16) ----------------

__global__ void pack_x(const float* __restrict__ word,
                       const float* __restrict__ tag,
                       const float* __restrict__ rel,
                       unsigned short* __restrict__ xcat) {
  int idx = blockIdx.x * 256 + threadIdx.x;       // N*KPAD
  if (idx >= NROWS * KPAD) return;
  int n = idx / KPAD, c = idx % KPAD;
  float v = 0.f;
  if (c < 300)      v = word[n * 300 + c];
  else if (c < 350) v = tag[n * 50 + (c - 300)];
  else if (c < 400) v = rel[n * 50 + (c - 350)];
  xcat[idx] = f2b(v);
}

__global__ void pack_w(const float* __restrict__ Ww,
                       const float* __restrict__ Wt,
                       const float* __restrict__ Wr,
                       unsigned short* __restrict__ Wcat) {
  int idx = blockIdx.x * 256 + threadIdx.x;       // 2560*KPAD
  if (idx >= GATES * HDIM * KPAD) return;
  int gh = idx / KPAD;
  int c = idx % KPAD;
  float v = 0.f;
  if (c < 300)      v = Ww[gh * 300 + c];
  else if (c < 350) v = Wt[gh * 50 + (c - 300)];
  else if (c < 400) v = Wr[gh * 50 + (c - 350)];
  Wcat[idx] = f2b(v);
}

__global__ void cvt_w4(const float* __restrict__ a, const float* __restrict__ b,
                       const float* __restrict__ c, const float* __restrict__ d,
                       unsigned short* oa, unsigned short* ob,
                       unsigned short* oc, unsigned short* od) {
  const float* in; unsigned short* out;
  switch (blockIdx.y) {
    case 0: in = a; out = oa; break;
    case 1: in = b; out = ob; break;
    case 2: in = c; out = oc; break;
    default: in = d; out = od; break;
  }
  int i = (blockIdx.x * 256 + threadIdx.x) * 4;   // 1310720 elems
  float4 v = *(const float4*)(in + i);
  ushort4 o;
  o.x = f2b(v.x); o.y = f2b(v.y); o.z = f2b(v.z); o.w = f2b(v.w);
  *(ushort4*)(out + i) = o;
}

__global__ void cvt_x2(const float* __restrict__ a, const float* __restrict__ b,
                       unsigned short* oa, unsigned short* ob) {
  const float* in = blockIdx.y ? b : a;
  unsigned short* out = blockIdx.y ? ob : oa;
  int i = (blockIdx.x * 256 + threadIdx.x) * 4;   // 8388608 elems
  float4 v = *(const float4*)(in + i);
  ushort4 o;
  o.x = f2b(v.x); o.y = f2b(v.y); o.z = f2b(v.z); o.w = f2b(v.w);
  *(ushort4*)(out + i) = o;
}

__global__ void pack_bias(const float* __restrict__ bw, const float* __restrict__ bt,
                          const float* __restrict__ br, const float* __restrict__ bh,
                          const float* __restrict__ bl, const float* __restrict__ bhp,
                          const float* __restrict__ bk,
                          float* bias0, float* bias1, float* bias2, float* biasD) {
  int i = blockIdx.x * 256 + threadIdx.x;
  if (i < GATES * HDIM) {
    bias0[i] = bw[i] + bt[i] + br[i];
    bias1[i] = bh[i];
    bias2[i] = bl[i];
    biasD[i] = bhp[i] + bk[i];
  }
}

// ---------------- GEMM: 256x256 tile, BK=32, 8 waves, 2-phase/K-tile ---------
// Out = tanh(A*W^T + bias).  W stacked [2560][ld]; grid (64,10); gate = gcol0>>9.
// ld/S runtime (stage1: 416/13, stages2-3: 512/16).

__global__ __launch_bounds__(512, 2) void gemm_big(
    const unsigned short* __restrict__ A1,
    const unsigned short* __restrict__ W1,
    const float* __restrict__ bias,
    unsigned short* __restrict__ Out,
    int aPerGate, int S, int ld)
{
  __shared__ __align__(16) unsigned short Abuf[2][256 * 32];
  __shared__ __align__(16) unsigned short Bbuf[2][256 * 32];

  const int t = threadIdx.x;
  const int row0  = blockIdx.x * 256;
  const int gcol0 = blockIdx.y * 256;          // [0,2560)
  const int g = gcol0 >> 9;
  const size_t aslab = aPerGate ? (size_t)g * NROWS * ld : 0;

  const int wid = t >> 6, l = t & 63;
  const int wrow = (wid >> 2) * 128;
  const int wcol = (wid & 3) * 64;
  const int fr = l & 15, q = l >> 4;

  f32x4 acc[8][4];
#pragma unroll
  for (int mi = 0; mi < 8; ++mi)
#pragma unroll
    for (int ni = 0; ni < 4; ++ni)
      acc[mi][ni] = (f32x4){0.f, 0.f, 0.f, 0.f};

  auto stage = [&](int c, int buf) {
    const int kloc = c * 32;
#pragma unroll
    for (int j = 0; j < 2; ++j) {
      const int r  = j * 128 + (t >> 2);
      const int sg = ((t & 3) ^ (r & 3)) * 8;
      gload_lds16(A1 + aslab + (size_t)(row0 + r) * ld + kloc + sg,  &Abuf[buf][j * 4096 + t * 8]);
      gload_lds16(W1 + (size_t)(gcol0 + r) * ld + kloc + sg, &Bbuf[buf][j * 4096 + t * 8]);
    }
  };

  stage(0, 0);
  asm volatile("s_waitcnt vmcnt(0)" ::: "memory");
  __builtin_amdgcn_s_barrier();

  bf16x8 bq[4];
  for (int s = 0; s < S; ++s) {
    const int buf = s & 1;
#pragma unroll
    for (int p = 0; p < 2; ++p) {
      bf16x8 af[4];
#pragma unroll
      for (int mi = 0; mi < 4; ++mi) {
        const int r = wrow + (p * 4 + mi) * 16 + fr;
        af[mi] = *reinterpret_cast<const bf16x8*>(&Abuf[buf][r * 32 + ((q ^ (r & 3)) * 8)]);
      }
      if (p == 0) {
#pragma unroll
        for (int ni = 0; ni < 4; ++ni) {
          const int r = wcol + ni * 16 + fr;
          bq[ni] = *reinterpret_cast<const bf16x8*>(&Bbuf[buf][r * 32 + ((q ^ (r & 3)) * 8)]);
        }
        if (s + 1 < S) stage(s + 1, buf ^ 1);
      }
      asm volatile("s_waitcnt lgkmcnt(0)" ::: "memory");
      __builtin_amdgcn_sched_barrier(0);
      __builtin_amdgcn_s_setprio(1);
#pragma unroll
      for (int mi = 0; mi < 4; ++mi)
#pragma unroll
        for (int ni = 0; ni < 4; ++ni)
          acc[p * 4 + mi][ni] = __builtin_amdgcn_mfma_f32_16x16x32_bf16(af[mi], bq[ni], acc[p * 4 + mi][ni], 0, 0, 0);
      __builtin_amdgcn_s_setprio(0);
      if (p == 0) __builtin_amdgcn_s_barrier();
    }
    asm volatile("s_waitcnt vmcnt(0)" ::: "memory");
    __builtin_amdgcn_s_barrier();
  }

  // epilogue: C/D col=lane&15, row=q*4+j
  const size_t NM = (size_t)NROWS * HDIM;
  unsigned short* outg = Out + (size_t)g * NM;
  const int colbase = gcol0 & 511;
#pragma unroll
  for (int mi = 0; mi < 8; ++mi) {
#pragma unroll
    for (int ni = 0; ni < 4; ++ni) {
      const int colLoc = colbase + wcol + ni * 16 + fr;
      const float bb = bias[g * HDIM + colLoc];
#pragma unroll
      for (int j = 0; j < 4; ++j) {
        const int nrow = row0 + wrow + mi * 16 + q * 4 + j;
        outg[(size_t)nrow * HDIM + colLoc] = f2b(fast_tanh(acc[mi][ni][j] + bb));
      }
    }
  }
}

// ---------------- fused gate GEMM + LSTM combine -----------------------------
// Block = 128x128 output tile, 512 thr (8 waves as 2Mx4N, wave 64x32).
// Loops gates in order u,i,f_down,f_left,o: per gate K=1024 GEMM
// (hprev|k vs Whp[g]|Wk[g]), epilogue folds biasD + m[g] and accumulates
// c = i*u + f*q + fl*cp in registers; o finalizes h = o*tanh(c).
// Eliminates the gates buffer (84 MB write + 84 MB read) and one dispatch.

__global__ __launch_bounds__(512, 2) void gate_combine(
    const unsigned short* __restrict__ hprevb, const unsigned short* __restrict__ kb,
    const unsigned short* __restrict__ Whp, const unsigned short* __restrict__ Wk,
    const float* __restrict__ biasD,
    const unsigned short* __restrict__ mbuf,   // [G][N][512] from stage C
    const float* __restrict__ qin, const float* __restrict__ cpin,
    float* __restrict__ out)
{
  __shared__ __align__(16) unsigned short Abuf[2][128 * 32];   // 8 KB each
  __shared__ __align__(16) unsigned short Bbuf[2][128 * 32];

  const size_t NM = (size_t)NROWS * HDIM;
  const int t = threadIdx.x;
  const int row0 = blockIdx.x * 128, col0 = blockIdx.y * 128;
  const int wid = t >> 6, l = t & 63;
  const int wrow = (wid >> 2) * 64, wcol = (wid & 3) * 32;
  const int fr = l & 15, qq = l >> 4;
  const int sr = t >> 2, ssl = t & 3;
  const int sgo = (ssl ^ ((sr >> 1) & 3)) * 8;   // inverse-swizzled source slot

  f32x4 cacc[4][2], uval[4][2];

#pragma unroll
  for (int gi = 0; gi < 5; ++gi) {
    const int g = (gi == 0) ? 4 : (gi - 1);      // process u first, o last
    const size_t wsl = (size_t)g * HDIM * HDIM;

    f32x4 acc[4][2];
#pragma unroll
    for (int mi = 0; mi < 4; ++mi)
#pragma unroll
      for (int ni = 0; ni < 2; ++ni)
        acc[mi][ni] = (f32x4){0.f, 0.f, 0.f, 0.f};

    auto stage = [&](int c, int buf) {
      const unsigned short* Ab; const unsigned short* Wb; int kloc;
      if (c >= 16) { Ab = kb;     Wb = Wk + wsl;  kloc = (c - 16) * 32; }
      else         { Ab = hprevb; Wb = Whp + wsl; kloc = c * 32; }
      gload_lds16(Ab + (size_t)(row0 + sr) * HDIM + kloc + sgo, &Abuf[buf][t * 8]);
      gload_lds16(Wb + (size_t)(col0 + sr) * HDIM + kloc + sgo, &Bbuf[buf][t * 8]);
    };

    stage(0, 0);
    asm volatile("s_waitcnt vmcnt(0)" ::: "memory");
    __syncthreads();

    for (int s = 0; s < 32; ++s) {
      if (s + 1 < 32) stage(s + 1, (s + 1) & 1);
      const int buf = s & 1;
      bf16x8 af[4], bf2[2];
#pragma unroll
      for (int mi = 0; mi < 4; ++mi) {
        const int r = wrow + mi * 16 + fr;
        af[mi] = *reinterpret_cast<const bf16x8*>(&Abuf[buf][r * 32 + ((qq ^ ((r >> 1) & 3)) * 8)]);
      }
#pragma unroll
      for (int ni = 0; ni < 2; ++ni) {
        const int r = wcol + ni * 16 + fr;
        bf2[ni] = *reinterpret_cast<const bf16x8*>(&Bbuf[buf][r * 32 + ((qq ^ ((r >> 1) & 3)) * 8)]);
      }
      __builtin_amdgcn_s_setprio(1);
#pragma unroll
      for (int mi = 0; mi < 4; ++mi)
#pragma unroll
        for (int ni = 0; ni < 2; ++ni)
          acc[mi][ni] = __builtin_amdgcn_mfma_f32_16x16x32_bf16(af[mi], bf2[ni], acc[mi][ni], 0, 0, 0);
      __builtin_amdgcn_s_setprio(0);
      __syncthreads();   // drains vmcnt+lgkmcnt; next buf ready, cur free
    }

    // per-gate epilogue (global only, no LDS)
    const unsigned short* mg = mbuf + (size_t)g * NM;
#pragma unroll
    for (int mi = 0; mi < 4; ++mi) {
#pragma unroll
      for (int ni = 0; ni < 2; ++ni) {
        const int col = col0 + wcol + ni * 16 + fr;
        const float bd = biasD[g * HDIM + col];
#pragma unroll
        for (int j = 0; j < 4; ++j) {
          const int row = row0 + wrow + mi * 16 + qq * 4 + j;
          const float pre = acc[mi][ni][j] + bd + b2f(mg[(size_t)row * HDIM + col]);
          if (gi == 0) {                // u
            uval[mi][ni][j] = fast_tanh(pre);
          } else if (gi == 1) {         // i
            cacc[mi][ni][j] = fast_sigmoid(pre) * uval[mi][ni][j];
          } else if (gi == 2) {         // f_down
            cacc[mi][ni][j] += fast_sigmoid(pre) * qin[(size_t)row * HDIM + col];
          } else if (gi == 3) {         // f_left
            cacc[mi][ni][j] += fast_sigmoid(pre) * cpin[(size_t)row * HDIM + col];
          } else {                      // o: finalize
            const float c = cacc[mi][ni][j];
            out[(size_t)row * HDIM + col]      = fast_sigmoid(pre) * fast_tanh(c);
            out[NM + (size_t)row * HDIM + col] = c;
          }
        }
      }
    }
  }
}

// ---------------- launch ----------------

extern "C" void kernel_launch(void* const* d_in, const int* in_sizes, int n_in,
                              void* d_out, int out_size, void* d_ws, size_t ws_size,
                              hipStream_t stream) {
  const float* word  = (const float*)d_in[0];
  const float* tag   = (const float*)d_in[1];
  const float* rel   = (const float*)d_in[2];
  const float* kin   = (const float*)d_in[3];
  const float* qin   = (const float*)d_in[4];
  const float* hprev = (const float*)d_in[5];
  const float* cprev = (const float*)d_in[6];
  const float* Ww    = (const float*)d_in[7];
  const float* bw    = (const float*)d_in[8];
  const float* Wt    = (const float*)d_in[9];
  const float* bt    = (const float*)d_in[10];
  const float* Wr    = (const float*)d_in[11];
  const float* br    = (const float*)d_in[12];
  const float* Wh    = (const float*)d_in[13];
  const float* bh    = (const float*)d_in[14];
  const float* Wl    = (const float*)d_in[15];
  const float* bl    = (const float*)d_in[16];
  const float* Whp   = (const float*)d_in[17];
  const float* bhp   = (const float*)d_in[18];
  const float* Wk    = (const float*)d_in[19];
  const float* bk    = (const float*)d_in[20];

  char* ws = (char*)d_ws;
  unsigned short* xcat   = (unsigned short*)(ws);                 // 13,631,488 B
  unsigned short* Wcat   = (unsigned short*)(ws + 13631488);      //  2,129,920 B
  unsigned short* Whb    = (unsigned short*)(ws + 15761408);      //  2,621,440 B
  unsigned short* Wlb    = (unsigned short*)(ws + 18382848);
  unsigned short* Whpb   = (unsigned short*)(ws + 21004288);
  unsigned short* Wkb    = (unsigned short*)(ws + 23625728);
  unsigned short* hprevb = (unsigned short*)(ws + 26247168);      // 16,777,216 B
  unsigned short* kb16   = (unsigned short*)(ws + 43024384);      // 16,777,216 B
  float* bias0           = (float*)(ws + 59801600);
  float* bias1           = (float*)(ws + 59811840);
  float* bias2           = (float*)(ws + 59822080);
  float* biasD           = (float*)(ws + 59832320);
  unsigned short* bufA   = (unsigned short*)(ws + 59842560);      // 83,886,080 B
  unsigned short* bufB   = (unsigned short*)(ws + 143728640);     // 83,886,080 B
  // total: 227,614,720 B

  pack_x<<<26624, 256, 0, stream>>>(word, tag, rel, xcat);
  pack_w<<<4160, 256, 0, stream>>>(Ww, Wt, Wr, Wcat);
  cvt_w4<<<dim3(1280, 4), 256, 0, stream>>>(Wh, Wl, Whp, Wk, Whb, Wlb, Whpb, Wkb);
  cvt_x2<<<dim3(8192, 2), 256, 0, stream>>>(hprev, kin, hprevb, kb16);
  pack_bias<<<10, 256, 0, stream>>>(bw, bt, br, bh, bl, bhp, bk, bias0, bias1, bias2, biasD);

  dim3 grid(NROWS / 256, (GATES * HDIM) / 256);   // 64 x 10
  // h0 = tanh(xcat W0^T + b0)            K=416 (13 tiles)
  gemm_big<<<grid, 512, 0, stream>>>(xcat, Wcat, bias0, bufA, 0, 13, KPAD);
  // h1 = tanh(h0 Whid^T + bhid)          K=512
  gemm_big<<<grid, 512, 0, stream>>>(bufA, Whb, bias1, bufB, 1, 16, HDIM);
  // m = tanh(h1 Wlast^T + blast)         K=512
  gemm_big<<<grid, 512, 0, stream>>>(bufB, Wlb, bias2, bufA, 1, 16, HDIM);
  // gates+combine fused: c = i*u + f_down*q + f_left*c_prev ; h = o*tanh(c)
  gate_combine<<<dim3(NROWS / 128, HDIM / 128), 512, 0, stream>>>(
      hprevb, kb16, Whpb, Wkb, biasD, bufA, qin, cprev, (float*)d_out);
}